// Round 1
// baseline (439.881 us; speedup 1.0000x reference)
//
#include <hip/hip_runtime.h>
#include <hip/hip_bf16.h>

// y = (fq_per_token(x) @ fq_per_channel(w)^T) + b
// Exact int8 factorization: y[m,n] = sx[m]*sw[n]*dot_i32(qx[m,:],qw[n,:]) + b[n]

#define K_DIM 4096
#define N_DIM 4096

typedef int v4i __attribute__((ext_vector_type(4)));

__device__ __forceinline__ void cp16(void* lds, const void* g) {
    __builtin_amdgcn_global_load_lds(
        (const __attribute__((address_space(1))) void*)g,
        (__attribute__((address_space(3))) void*)lds, 16, 0, 0);
}

// ---------------------------------------------------------------------------
// Per-row symmetric int8 fake-quant: one block per row of 4096 fp32.
// scale = max(amax/127, 1e-8); q = clamp(rint(x/scale), -128, 127)
// ---------------------------------------------------------------------------
__global__ __launch_bounds__(256) void quant_rows_kernel(
    const float* __restrict__ src, char* __restrict__ qdst,
    float* __restrict__ sdst) {
    const int row = blockIdx.x;
    const int tid = threadIdx.x;
    const float* rp = src + (size_t)row * 4096;

    float4 v[4];
#pragma unroll
    for (int i = 0; i < 4; ++i)
        v[i] = *(const float4*)(rp + 4 * (tid + 256 * i));

    float m = 0.0f;
#pragma unroll
    for (int i = 0; i < 4; ++i) {
        m = fmaxf(m, fmaxf(fmaxf(fabsf(v[i].x), fabsf(v[i].y)),
                           fmaxf(fabsf(v[i].z), fabsf(v[i].w))));
    }
#pragma unroll
    for (int off = 32; off > 0; off >>= 1)
        m = fmaxf(m, __shfl_down(m, off));

    __shared__ float red[4];
    if ((tid & 63) == 0) red[tid >> 6] = m;
    __syncthreads();
    const float amax = fmaxf(fmaxf(red[0], red[1]), fmaxf(red[2], red[3]));
    const float scale = fmaxf(amax / 127.0f, 1e-8f);

    int* qout = (int*)(qdst + (size_t)row * 4096);
#pragma unroll
    for (int i = 0; i < 4; ++i) {
        int q0 = (int)fminf(fmaxf(rintf(v[i].x / scale), -128.0f), 127.0f);
        int q1 = (int)fminf(fmaxf(rintf(v[i].y / scale), -128.0f), 127.0f);
        int q2 = (int)fminf(fmaxf(rintf(v[i].z / scale), -128.0f), 127.0f);
        int q3 = (int)fminf(fmaxf(rintf(v[i].w / scale), -128.0f), 127.0f);
        qout[tid + 256 * i] =
            (q0 & 255) | ((q1 & 255) << 8) | ((q2 & 255) << 16) | ((q3 & 255) << 24);
    }
    if (tid == 0) sdst[row] = scale;
}

// ---------------------------------------------------------------------------
// int8 GEMM: C[m,n] = sx[m]*sw[n]*sum_k qx[m,k]*qw[n,k] + bias[n]
// Both operands K-contiguous (B^T layout). m97 structure:
//   128x128 block tile, BK=64, 256 threads = 4 waves (2x2 of 64x64),
//   each wave: 4x4 tiles of mfma_i32_16x16x64_i8.
//   Staging via global_load_lds width=16; LDS chunk XOR-swizzle (kc ^ row&3)
//   so the ds_read_b128 fragment reads avoid 4-way bank aliasing.
// ---------------------------------------------------------------------------
__global__ __launch_bounds__(256) void gemm_i8_kernel(
    const char* __restrict__ qx, const char* __restrict__ qw,
    const float* __restrict__ sx, const float* __restrict__ sw,
    const float* __restrict__ bias, float* __restrict__ y) {

    __shared__ __align__(16) char As[128 * 64];
    __shared__ __align__(16) char Bs[128 * 64];

    const int tid = threadIdx.x;
    const int wave = tid >> 6;
    const int lane = tid & 63;
    const int ln = lane & 15;   // MFMA "column" index within 16
    const int lg = lane >> 4;   // MFMA lane-group 0..3
    const int wm = wave & 1;    // wave tile m (0..1)
    const int wn = wave >> 1;   // wave tile n (0..1)

    const int bm = blockIdx.y;
    const int bn = blockIdx.x;

    const char* aBase = qx + (size_t)bm * 128 * K_DIM;
    const char* bBase = qw + (size_t)bn * 128 * K_DIM;

    // Staging: 512 chunks of 16B per tile; thread t handles chunks t and t+256.
    // LDS chunk c holds global (row=c>>2, kchunk=(c&3)^(row&3)).
    const int c0 = tid;
    const int c1 = tid + 256;
    const int r0 = c0 >> 2;
    const int r1 = c1 >> 2;
    const int kc0 = (c0 & 3) ^ (r0 & 3);
    const int kc1 = (c1 & 3) ^ (r1 & 3);

    v4i acc[4][4] = {};

    // Fragment read offsets: row = tileBase + ln, kchunk = lg, swizzled addr.
    const int kxor = (lg ^ (ln & 3)) << 4;
    int aOff[4], bOff[4];
#pragma unroll
    for (int t = 0; t < 4; ++t) {
        aOff[t] = (wm * 64 + t * 16 + ln) * 64 + kxor;
        bOff[t] = (wn * 64 + t * 16 + ln) * 64 + kxor;
    }

    for (int k0 = 0; k0 < K_DIM; k0 += 64) {
        cp16(As + c0 * 16, aBase + (size_t)r0 * K_DIM + k0 + kc0 * 16);
        cp16(As + c1 * 16, aBase + (size_t)r1 * K_DIM + k0 + kc1 * 16);
        cp16(Bs + c0 * 16, bBase + (size_t)r0 * K_DIM + k0 + kc0 * 16);
        cp16(Bs + c1 * 16, bBase + (size_t)r1 * K_DIM + k0 + kc1 * 16);
        __syncthreads();   // drains vmcnt: staged data visible

        v4i afr[4], bfr[4];
#pragma unroll
        for (int t = 0; t < 4; ++t) afr[t] = *(const v4i*)(As + aOff[t]);
#pragma unroll
        for (int t = 0; t < 4; ++t) bfr[t] = *(const v4i*)(Bs + bOff[t]);

#pragma unroll
        for (int mt = 0; mt < 4; ++mt)
#pragma unroll
            for (int nt = 0; nt < 4; ++nt)
                acc[mt][nt] = __builtin_amdgcn_mfma_i32_16x16x64_i8(
                    afr[mt], bfr[nt], acc[mt][nt], 0, 0, 0);

        __syncthreads();   // all reads done before next overwrite
    }

    // Epilogue. C/D layout (16x16): col = lane&15, row = (lane>>4)*4 + reg.
    const int m_base = bm * 128 + wm * 64;
    const int n_base = bn * 128 + wn * 64;

    float sxr[4][4];
#pragma unroll
    for (int mt = 0; mt < 4; ++mt)
#pragma unroll
        for (int r = 0; r < 4; ++r)
            sxr[mt][r] = sx[m_base + mt * 16 + lg * 4 + r];

#pragma unroll
    for (int nt = 0; nt < 4; ++nt) {
        const int n = n_base + nt * 16 + ln;
        const float swv = sw[n];
        const float bv = bias[n];
#pragma unroll
        for (int mt = 0; mt < 4; ++mt) {
            const int row = m_base + mt * 16 + lg * 4;
#pragma unroll
            for (int r = 0; r < 4; ++r) {
                y[(size_t)(row + r) * N_DIM + n] =
                    (float)acc[mt][nt][r] * sxr[mt][r] * swv + bv;
            }
        }
    }
}

extern "C" void kernel_launch(void* const* d_in, const int* in_sizes, int n_in,
                              void* d_out, int out_size, void* d_ws, size_t ws_size,
                              hipStream_t stream) {
    const float* x = (const float*)d_in[0];   // [B*S, 4096] = [8192, 4096]
    const float* w = (const float*)d_in[1];   // [4096, 4096]
    const float* b = (const float*)d_in[2];   // [4096]
    float* y = (float*)d_out;                 // [8192, 4096]

    const int M = in_sizes[0] / K_DIM;        // 8192
    const int O = in_sizes[1] / K_DIM;        // 4096

    // Workspace layout
    char* qx = (char*)d_ws;                           // M*4096 int8
    char* qw = qx + (size_t)M * K_DIM;                // O*4096 int8
    float* sx = (float*)(qw + (size_t)O * K_DIM);     // M floats
    float* sw = sx + M;                               // O floats

    quant_rows_kernel<<<M, 256, 0, stream>>>(x, qx, sx);
    quant_rows_kernel<<<O, 256, 0, stream>>>(w, qw, sw);

    dim3 grid(N_DIM / 128, M / 128);
    gemm_i8_kernel<<<grid, 256, 0, stream>>>(qx, qw, sx, sw, b, y);
}

// Round 2
// 429.759 us; speedup vs baseline: 1.0236x; 1.0236x over previous
//
#include <hip/hip_runtime.h>
#include <hip/hip_bf16.h>

// y = (fq_per_token(x) @ fq_per_channel(w)^T) + b
// Exact int8 factorization: y[m,n] = sx[m]*sw[n]*dot_i32(qx[m,:],qw[n,:]) + b[n]

#define K_DIM 4096
#define N_DIM 4096

typedef int v4i __attribute__((ext_vector_type(4)));

__device__ __forceinline__ void cp16(void* lds, const void* g) {
    __builtin_amdgcn_global_load_lds(
        (const __attribute__((address_space(1))) void*)g,
        (__attribute__((address_space(3))) void*)lds, 16, 0, 0);
}

// ---------------------------------------------------------------------------
// Per-row symmetric int8 fake-quant, x and w merged into one grid.
// Blocks [0, M) quantize x rows; blocks [M, M+O) quantize w rows.
// scale = max(amax/127, 1e-8); q = clamp(rint(v/scale), -128, 127)
// ---------------------------------------------------------------------------
__global__ __launch_bounds__(256) void quant_rows_kernel(
    const float* __restrict__ x, const float* __restrict__ w, int M,
    char* __restrict__ qx, char* __restrict__ qw,
    float* __restrict__ sx, float* __restrict__ sw) {
    const int blk = blockIdx.x;
    const bool is_x = blk < M;
    const int row = is_x ? blk : blk - M;
    const float* rp = (is_x ? x : w) + (size_t)row * 4096;
    char* qdst = is_x ? qx : qw;
    float* sdst = is_x ? sx : sw;

    const int tid = threadIdx.x;

    float4 v[4];
#pragma unroll
    for (int i = 0; i < 4; ++i)
        v[i] = *(const float4*)(rp + 4 * (tid + 256 * i));

    float m = 0.0f;
#pragma unroll
    for (int i = 0; i < 4; ++i) {
        m = fmaxf(m, fmaxf(fmaxf(fabsf(v[i].x), fabsf(v[i].y)),
                           fmaxf(fabsf(v[i].z), fabsf(v[i].w))));
    }
#pragma unroll
    for (int off = 32; off > 0; off >>= 1)
        m = fmaxf(m, __shfl_down(m, off));

    __shared__ float red[4];
    if ((tid & 63) == 0) red[tid >> 6] = m;
    __syncthreads();
    const float amax = fmaxf(fmaxf(red[0], red[1]), fmaxf(red[2], red[3]));
    const float scale = fmaxf(amax / 127.0f, 1e-8f);

    int* qout = (int*)(qdst + (size_t)row * 4096);
#pragma unroll
    for (int i = 0; i < 4; ++i) {
        int q0 = (int)fminf(fmaxf(rintf(v[i].x / scale), -128.0f), 127.0f);
        int q1 = (int)fminf(fmaxf(rintf(v[i].y / scale), -128.0f), 127.0f);
        int q2 = (int)fminf(fmaxf(rintf(v[i].z / scale), -128.0f), 127.0f);
        int q3 = (int)fminf(fmaxf(rintf(v[i].w / scale), -128.0f), 127.0f);
        qout[tid + 256 * i] =
            (q0 & 255) | ((q1 & 255) << 8) | ((q2 & 255) << 16) | ((q3 & 255) << 24);
    }
    if (tid == 0) sdst[row] = scale;
}

// ---------------------------------------------------------------------------
// int8 GEMM: C[m,n] = sx[m]*sw[n]*sum_k qx[m,k]*qw[n,k] + bias[n]
// m97 structure: 128x128 block tile, BK=64, 4 waves (2x2 of 64x64),
// each wave 4x4 of mfma_i32_16x16x64_i8, global_load_lds width=16 staging.
//
// LDS swizzle (bank-conflict-free b128 reads):
//   b128 wave read services 8 lanes/cycle; need each consecutive 8-lane
//   group to hit 8 distinct 16B bank-groups. bank-group = (row*4+kc) mod 8
//   = 4*(ln&1) + kc. Store kchunk kc of row r at LDS sub-chunk
//   kc ^ ((r>>1)&3); fragment read uses kxor = lg ^ ((ln>>1)&3), giving
//   lanes 0..7 groups {lg,4+lg,lg^1,4+lg^1,lg^2,4+lg^2,lg^3,4+lg^3} = all 8.
//   (Round-1 swizzle kc^(r&3) left 2-way collisions: 1.68e7 conflict cycles.)
// ---------------------------------------------------------------------------
__global__ __launch_bounds__(256) void gemm_i8_kernel(
    const char* __restrict__ qx, const char* __restrict__ qw,
    const float* __restrict__ sx, const float* __restrict__ sw,
    const float* __restrict__ bias, float* __restrict__ y) {

    __shared__ __align__(16) char As[128 * 64];
    __shared__ __align__(16) char Bs[128 * 64];

    const int tid = threadIdx.x;
    const int wave = tid >> 6;
    const int lane = tid & 63;
    const int ln = lane & 15;   // MFMA "column" index within 16
    const int lg = lane >> 4;   // MFMA lane-group 0..3
    const int wm = wave & 1;    // wave tile m (0..1)
    const int wn = wave >> 1;   // wave tile n (0..1)

    const int bm = blockIdx.y;
    const int bn = blockIdx.x;

    const char* aBase = qx + (size_t)bm * 128 * K_DIM;
    const char* bBase = qw + (size_t)bn * 128 * K_DIM;

    // Staging: 512 chunks of 16B per tile; thread t handles LDS chunks t and
    // t+256 (wave-contiguous dest, required by global_load_lds). LDS chunk c
    // holds global (row = c>>2, kchunk = (c&3) ^ ((c>>3)&3)).
    const int c0 = tid;
    const int c1 = tid + 256;
    const int r0 = c0 >> 2;
    const int r1 = c1 >> 2;
    const int kc0 = (c0 & 3) ^ ((c0 >> 3) & 3);
    const int kc1 = (c1 & 3) ^ ((c1 >> 3) & 3);

    v4i acc[4][4] = {};

    // Fragment read: row = tileBase + ln, kchunk = lg, swizzled sub-chunk.
    const int kxor = (lg ^ ((ln >> 1) & 3)) << 4;
    int aOff[4], bOff[4];
#pragma unroll
    for (int t = 0; t < 4; ++t) {
        aOff[t] = (wm * 64 + t * 16 + ln) * 64 + kxor;
        bOff[t] = (wn * 64 + t * 16 + ln) * 64 + kxor;
    }

    for (int k0 = 0; k0 < K_DIM; k0 += 64) {
        cp16(As + c0 * 16, aBase + (size_t)r0 * K_DIM + k0 + kc0 * 16);
        cp16(As + c1 * 16, aBase + (size_t)r1 * K_DIM + k0 + kc1 * 16);
        cp16(Bs + c0 * 16, bBase + (size_t)r0 * K_DIM + k0 + kc0 * 16);
        cp16(Bs + c1 * 16, bBase + (size_t)r1 * K_DIM + k0 + kc1 * 16);
        __syncthreads();   // drains vmcnt: staged data visible

        v4i afr[4], bfr[4];
#pragma unroll
        for (int t = 0; t < 4; ++t) afr[t] = *(const v4i*)(As + aOff[t]);
#pragma unroll
        for (int t = 0; t < 4; ++t) bfr[t] = *(const v4i*)(Bs + bOff[t]);

#pragma unroll
        for (int mt = 0; mt < 4; ++mt)
#pragma unroll
            for (int nt = 0; nt < 4; ++nt)
                acc[mt][nt] = __builtin_amdgcn_mfma_i32_16x16x64_i8(
                    afr[mt], bfr[nt], acc[mt][nt], 0, 0, 0);

        __syncthreads();   // all reads done before next overwrite
    }

    // Epilogue. C/D layout (16x16): col = lane&15, row = (lane>>4)*4 + reg.
    const int m_base = bm * 128 + wm * 64;
    const int n_base = bn * 128 + wn * 64;

    float sxr[4][4];
#pragma unroll
    for (int mt = 0; mt < 4; ++mt)
#pragma unroll
        for (int r = 0; r < 4; ++r)
            sxr[mt][r] = sx[m_base + mt * 16 + lg * 4 + r];

#pragma unroll
    for (int nt = 0; nt < 4; ++nt) {
        const int n = n_base + nt * 16 + ln;
        const float swv = sw[n];
        const float bv = bias[n];
#pragma unroll
        for (int mt = 0; mt < 4; ++mt) {
            const int row = m_base + mt * 16 + lg * 4;
#pragma unroll
            for (int r = 0; r < 4; ++r) {
                y[(size_t)(row + r) * N_DIM + n] =
                    (float)acc[mt][nt][r] * sxr[mt][r] * swv + bv;
            }
        }
    }
}

extern "C" void kernel_launch(void* const* d_in, const int* in_sizes, int n_in,
                              void* d_out, int out_size, void* d_ws, size_t ws_size,
                              hipStream_t stream) {
    const float* x = (const float*)d_in[0];   // [B*S, 4096] = [8192, 4096]
    const float* w = (const float*)d_in[1];   // [4096, 4096]
    const float* b = (const float*)d_in[2];   // [4096]
    float* y = (float*)d_out;                 // [8192, 4096]

    const int M = in_sizes[0] / K_DIM;        // 8192
    const int O = in_sizes[1] / K_DIM;        // 4096

    // Workspace layout
    char* qx = (char*)d_ws;                           // M*4096 int8
    char* qw = qx + (size_t)M * K_DIM;                // O*4096 int8
    float* sx = (float*)(qw + (size_t)O * K_DIM);     // M floats
    float* sw = sx + M;                               // O floats

    quant_rows_kernel<<<M + O, 256, 0, stream>>>(x, w, M, qx, qw, sx, sw);

    dim3 grid(N_DIM / 128, M / 128);
    gemm_i8_kernel<<<grid, 256, 0, stream>>>(qx, qw, sx, sw, b, y);
}